// Round 12
// baseline (150.803 us; speedup 1.0000x reference)
//
#include <hip/hip_runtime.h>
#include <hip/hip_bf16.h>

typedef __attribute__((ext_vector_type(4))) float f32x4;
typedef __attribute__((ext_vector_type(8))) short s16x8;
typedef __attribute__((ext_vector_type(4))) short s16x4;

static constexpr int Bn = 32;
static constexpr int Tn = 4096;
static constexpr int Dn = 256;
static constexpr int Un = 256;
static constexpr int CH = Tn / 64;   // 64 chunks per batch, 1 chunk per block

// HW bf16 cast (RTNE)
__device__ __forceinline__ ushort f2bf_hw(float f) {
    union { __hip_bfloat16 h; ushort u; } c;
    c.h = __float2bfloat16(f);
    return c.u;
}
__device__ __forceinline__ float bf2f(ushort u) {
    return __uint_as_float(((unsigned)u) << 16);
}
// 6-inst tanh: 1 - 2/(1+e^{2x})
__device__ __forceinline__ float tanh5(float x) {
    float t = __expf(2.0f * x);
    return 1.0f - __fdividef(2.0f, 1.0f + t);
}

// K0: prep. Blocks 0..255: W1T[u][d] = bf16(W1[d][u]). Blocks 256..287: qproj.
__global__ __launch_bounds__(256) void k_prep(const float* __restrict__ W1,
                                              ushort* __restrict__ W1T,
                                              const float* __restrict__ query,
                                              const float* __restrict__ W2,
                                              const float* __restrict__ b1,
                                              const float* __restrict__ b2,
                                              float* __restrict__ qb) {
    __shared__ float qs[Dn];
    if (blockIdx.x < 256) {
        const int u = blockIdx.x, d = threadIdx.x;
        W1T[u * Dn + d] = f2bf_hw(W1[d * Un + u]);
    } else {
        const int b = blockIdx.x - 256, u = threadIdx.x;
        qs[u] = query[b * Dn + u];
        __syncthreads();
        float acc = b1[u] + b2[u];
        #pragma unroll 8
        for (int d = 0; d < Dn; ++d) acc += qs[d] * W2[d * Un + u];
        qb[b * Un + u] = acc;
    }
}

// K1: unchanged from R11 (best known: 78 µs).
__global__ __launch_bounds__(256, 4) void k_fused(const float* __restrict__ values,
                                                  const ushort* __restrict__ W1T,
                                                  const float* __restrict__ qb,
                                                  const float* __restrict__ Vw,
                                                  const float* __restrict__ bV,
                                                  float* __restrict__ scores,
                                                  float* __restrict__ pm,
                                                  float* __restrict__ ps,
                                                  float* __restrict__ pctx) {
    __shared__ __align__(16) ushort Al[64][264];
    __shared__ float sred[4][64];
    __shared__ f32x4 cred[4][64];
    const int tid = threadIdx.x;
    const int b = blockIdx.y, c = blockIdx.x;
    const int t0 = c * 64;
    const int wid = tid >> 6, lane = tid & 63;
    const int l15 = lane & 15, hi = lane >> 4;

    const float* vbase = values + ((size_t)b * Tn + t0) * Dn;
    #pragma unroll
    for (int i = 0; i < 8; ++i) {
        int flat = i * 2048 + tid * 8;
        int row = flat >> 8, col = flat & 255;
        const float4 f0 = *(const float4*)&vbase[row * Dn + col];
        const float4 f1 = *(const float4*)&vbase[row * Dn + col + 4];
        s16x8 p;
        p[0] = (short)f2bf_hw(f0.x); p[1] = (short)f2bf_hw(f0.y);
        p[2] = (short)f2bf_hw(f0.z); p[3] = (short)f2bf_hw(f0.w);
        p[4] = (short)f2bf_hw(f1.x); p[5] = (short)f2bf_hw(f1.y);
        p[6] = (short)f2bf_hw(f1.z); p[7] = (short)f2bf_hw(f1.w);
        *(s16x8*)&Al[row][col] = p;
    }

    const ushort* wbase = W1T + (size_t)(wid * 64 + l15) * Dn + hi * 8;

    f32x4 acc[4][4];
    #pragma unroll
    for (int tt = 0; tt < 4; ++tt)
        #pragma unroll
        for (int ut = 0; ut < 4; ++ut) acc[tt][ut] = (f32x4){0.f, 0.f, 0.f, 0.f};

    s16x8 bfn0[4], bfn1[4];
    #pragma unroll
    for (int ut = 0; ut < 4; ++ut)
        bfn0[ut] = *(const s16x8*)&wbase[(size_t)ut * 16 * Dn];
    #pragma unroll
    for (int ut = 0; ut < 4; ++ut)
        bfn1[ut] = *(const s16x8*)&wbase[(size_t)ut * 16 * Dn + 32];

    __syncthreads();

    #pragma unroll
    for (int kc = 0; kc < 8; ++kc) {
        s16x8 bf[4];
        #pragma unroll
        for (int ut = 0; ut < 4; ++ut) { bf[ut] = bfn0[ut]; bfn0[ut] = bfn1[ut]; }
        if (kc < 6) {
            #pragma unroll
            for (int ut = 0; ut < 4; ++ut)
                bfn1[ut] = *(const s16x8*)&wbase[(size_t)ut * 16 * Dn + (kc + 2) * 32];
        }
        const int k0 = kc * 32;
        s16x8 af[4];
        #pragma unroll
        for (int tt = 0; tt < 4; ++tt)
            af[tt] = *(const s16x8*)&Al[tt * 16 + l15][k0 + hi * 8];
        #pragma unroll
        for (int tt = 0; tt < 4; ++tt)
            #pragma unroll
            for (int ut = 0; ut < 4; ++ut)
                acc[tt][ut] = __builtin_amdgcn_mfma_f32_16x16x32_bf16(af[tt], bf[ut], acc[tt][ut], 0, 0, 0);
    }

    float Vreg[4], qreg[4];
    #pragma unroll
    for (int ut = 0; ut < 4; ++ut) {
        int u = wid * 64 + ut * 16 + l15;
        Vreg[ut] = Vw[u];
        qreg[ut] = qb[b * Un + u];
    }

    float psc[4][4];
    #pragma unroll
    for (int tt = 0; tt < 4; ++tt)
        #pragma unroll
        for (int i = 0; i < 4; ++i) psc[tt][i] = 0.f;
    #pragma unroll
    for (int tt = 0; tt < 4; ++tt)
        #pragma unroll
        for (int ut = 0; ut < 4; ++ut)
            #pragma unroll
            for (int i = 0; i < 4; ++i)
                psc[tt][i] += tanh5(acc[tt][ut][i] + qreg[ut]) * Vreg[ut];

    #pragma unroll
    for (int tt = 0; tt < 4; ++tt)
        #pragma unroll
        for (int i = 0; i < 4; ++i) {
            float v = psc[tt][i];
            v += __shfl_xor(v, 1, 64);
            v += __shfl_xor(v, 2, 64);
            v += __shfl_xor(v, 4, 64);
            v += __shfl_xor(v, 8, 64);
            if (l15 == 0) sred[wid][tt * 16 + hi * 4 + i] = v;
        }
    __syncthreads();

    float s = sred[0][lane] + sred[1][lane] + sred[2][lane] + sred[3][lane] + bV[0];
    if (wid == 0) scores[b * Tn + t0 + lane] = s;
    float m = s;
    #pragma unroll
    for (int off = 32; off > 0; off >>= 1) m = fmaxf(m, __shfl_xor(m, off, 64));
    const float p = __expf(s - m);
    float S = p;
    #pragma unroll
    for (int off = 32; off > 0; off >>= 1) S += __shfl_xor(S, off, 64);

    const int d4 = lane * 4;
    f32x4 loc = (f32x4){0.f, 0.f, 0.f, 0.f};
    #pragma unroll
    for (int k = 0; k < 16; ++k) {
        const int t = wid + 4 * k;
        const float pk = __shfl(p, t, 64);
        const s16x4 v = *(const s16x4*)&Al[t][d4];
        loc[0] += pk * bf2f((ushort)v[0]);
        loc[1] += pk * bf2f((ushort)v[1]);
        loc[2] += pk * bf2f((ushort)v[2]);
        loc[3] += pk * bf2f((ushort)v[3]);
    }
    cred[wid][lane] = loc;
    __syncthreads();
    if (wid == 0) {
        const f32x4 o = cred[0][lane] + cred[1][lane] + cred[2][lane] + cred[3][lane];
        *(f32x4*)&pctx[((size_t)(b * CH + c)) * Dn + d4] = o;
    }
    if (tid == 0) { pm[b * CH + c] = m; ps[b * CH + c] = S; }
}

// PROBE: staging phase only, REP=8 distinct 64KB chunks per block (1 GB total).
// Same grid/waves/LDS/occupancy as k_fused. Keep-alives per rule 17.
// Readout: its dur_us and hbm_gbps row in the top-5 table.
__global__ __launch_bounds__(256, 4) void k_probe_stage(const float* __restrict__ values,
                                                        float* __restrict__ scratch) {
    __shared__ __align__(16) ushort Al[64][264];
    const int tid = threadIdx.x;
    const int b = blockIdx.y, c = blockIdx.x;
    float keep = 0.f;
    #pragma unroll 1
    for (int rep = 0; rep < 8; ++rep) {
        const int t0 = (c * 64 + rep * 512) & (Tn - 1);   // 8 distinct chunks/block
        const float* vbase = values + ((size_t)b * Tn + t0) * Dn;
        #pragma unroll
        for (int i = 0; i < 8; ++i) {
            int flat = i * 2048 + tid * 8;
            int row = flat >> 8, col = flat & 255;
            const float4 f0 = *(const float4*)&vbase[row * Dn + col];
            const float4 f1 = *(const float4*)&vbase[row * Dn + col + 4];
            s16x8 p;
            p[0] = (short)f2bf_hw(f0.x); p[1] = (short)f2bf_hw(f0.y);
            p[2] = (short)f2bf_hw(f0.z); p[3] = (short)f2bf_hw(f0.w);
            p[4] = (short)f2bf_hw(f1.x); p[5] = (short)f2bf_hw(f1.y);
            p[6] = (short)f2bf_hw(f1.z); p[7] = (short)f2bf_hw(f1.w);
            *(s16x8*)&Al[row][col] = p;
        }
        __syncthreads();                       // same drain as k_fused's B1
        float v = bf2f((ushort)Al[tid & 63][(tid >> 6) * 8 + rep]);
        asm volatile("" :: "v"(v));            // keep the tile live (rule 17)
        keep += v;
        __syncthreads();                       // protect next rep's overwrite
    }
    if (keep == 123456.789f) scratch[b * CH + c] = keep;  // never taken; anti-DCE
}

// K2: per-batch flash reduce over CH chunk partials.
__global__ __launch_bounds__(256) void k_reduce(const float* __restrict__ pm,
                                                const float* __restrict__ ps,
                                                const float* __restrict__ pctx,
                                                float* __restrict__ context,
                                                float* __restrict__ MS) {
    const int b = blockIdx.x, d = threadIdx.x;
    float M = -1e30f;
    #pragma unroll 8
    for (int c = 0; c < CH; ++c) M = fmaxf(M, pm[b * CH + c]);
    float S = 0.f, ctx = 0.f;
    #pragma unroll 4
    for (int c = 0; c < CH; ++c) {
        const float w = __expf(pm[b * CH + c] - M);
        S += w * ps[b * CH + c];
        ctx += w * pctx[((size_t)(b * CH + c)) * Dn + d];
    }
    context[b * Dn + d] = __fdividef(ctx, S);
    if (d == 0) { MS[b * 2] = M; MS[b * 2 + 1] = S; }
}

// K3: attn[b,t] = exp(score - M_b) / S_b, in place.
__global__ __launch_bounds__(256) void k_attn(float* __restrict__ attn,
                                              const float* __restrict__ MS) {
    const int b = blockIdx.y;
    const int base = b * Tn + blockIdx.x * 1024 + threadIdx.x * 4;
    const float M = MS[b * 2];
    const float invS = __fdividef(1.0f, MS[b * 2 + 1]);
    float4 s = *(const float4*)&attn[base];
    s.x = __expf(s.x - M) * invS;
    s.y = __expf(s.y - M) * invS;
    s.z = __expf(s.z - M) * invS;
    s.w = __expf(s.w - M) * invS;
    *(float4*)&attn[base] = s;
}

extern "C" void kernel_launch(void* const* d_in, const int* in_sizes, int n_in,
                              void* d_out, int out_size, void* d_ws, size_t ws_size,
                              hipStream_t stream) {
    const float* query  = (const float*)d_in[0];
    const float* values = (const float*)d_in[1];
    const float* W1     = (const float*)d_in[2];
    const float* b1     = (const float*)d_in[3];
    const float* W2     = (const float*)d_in[4];
    const float* b2     = (const float*)d_in[5];
    const float* Vw     = (const float*)d_in[6];
    const float* bV     = (const float*)d_in[7];

    float* context = (float*)d_out;            // [B,D]
    float* attn    = (float*)d_out + Bn * Dn;  // [B,T,1]

    float*  pctx = (float*)d_ws;                       // [B, CH, D] = 2 MB
    float*  pm   = pctx + (size_t)Bn * CH * Dn;        // [B, CH]
    float*  ps   = pm + Bn * CH;                       // [B, CH]
    float*  qb   = ps + Bn * CH;                       // [B, U]
    float*  MS   = qb + Bn * Un;                       // [B, 2]
    ushort* W1T  = (ushort*)(MS + Bn * 2);             // [U, D] bf16 = 128 KB
    float*  pscr = (float*)(W1T + Un * Dn);            // probe scratch [B*CH]

    k_prep<<<dim3(256 + Bn), dim3(256), 0, stream>>>(W1, W1T, query, W2, b1, b2, qb);
    k_fused<<<dim3(CH, Bn), dim3(256), 0, stream>>>(values, W1T, qb, Vw, bV,
                                                    attn, pm, ps, pctx);
    k_reduce<<<dim3(Bn), dim3(256), 0, stream>>>(pm, ps, pctx, context, MS);
    k_attn<<<dim3(Tn / 1024, Bn), dim3(256), 0, stream>>>(attn, MS);
    // diagnostic probe (inflates this round's dur_us on purpose)
    k_probe_stage<<<dim3(CH, Bn), dim3(256), 0, stream>>>(values, pscr);
}

// Round 13
// 96.479 us; speedup vs baseline: 1.5631x; 1.5631x over previous
//
#include <hip/hip_runtime.h>
#include <hip/hip_bf16.h>

typedef __attribute__((ext_vector_type(4))) float f32x4;
typedef __attribute__((ext_vector_type(8))) short s16x8;
typedef __attribute__((ext_vector_type(4))) short s16x4;

static constexpr int Bn = 32;
static constexpr int Tn = 4096;
static constexpr int Dn = 256;
static constexpr int Un = 256;
static constexpr int CH = Tn / 64;   // 64 chunks per batch, 1 chunk per block

// HW bf16 cast (RTNE)
__device__ __forceinline__ ushort f2bf_hw(float f) {
    union { __hip_bfloat16 h; ushort u; } c;
    c.h = __float2bfloat16(f);
    return c.u;
}
__device__ __forceinline__ float bf2f(ushort u) {
    return __uint_as_float(((unsigned)u) << 16);
}
// 6-inst tanh: 1 - 2/(1+e^{2x})
__device__ __forceinline__ float tanh5(float x) {
    float t = __expf(2.0f * x);
    return 1.0f - __fdividef(2.0f, 1.0f + t);
}

// K0: prep. Blocks 0..255: W1T[u][d] = bf16(W1[d][u]). Blocks 256..287: qproj.
__global__ __launch_bounds__(256) void k_prep(const float* __restrict__ W1,
                                              ushort* __restrict__ W1T,
                                              const float* __restrict__ query,
                                              const float* __restrict__ W2,
                                              const float* __restrict__ b1,
                                              const float* __restrict__ b2,
                                              float* __restrict__ qb) {
    __shared__ float qs[Dn];
    if (blockIdx.x < 256) {
        const int u = blockIdx.x, d = threadIdx.x;
        W1T[u * Dn + d] = f2bf_hw(W1[d * Un + u]);
    } else {
        const int b = blockIdx.x - 256, u = threadIdx.x;
        qs[u] = query[b * Dn + u];
        __syncthreads();
        float acc = b1[u] + b2[u];
        #pragma unroll 8
        for (int d = 0; d < Dn; ++d) acc += qs[d] * W2[d * Un + u];
        qb[b * Un + u] = acc;
    }
}

// K1: R11 skeleton at 8 waves/block (512 thr) for 24 waves/CU (6/SIMD).
// Wave (wr=wid>>2, wc=wid&3) owns 32t x 64u: acc[2][4] (32 VGPR), B ring
// depth-1 (32 VGPR) -> ~80 VGPR, capped by launch_bounds(512,6). Same LDS
// (38.9 KB), same barriers. Staging split across 8 waves. Deeper TLP is the
// single variable vs R11.
__global__ __launch_bounds__(512, 6) void k_fused(const float* __restrict__ values,
                                                  const ushort* __restrict__ W1T,
                                                  const float* __restrict__ qb,
                                                  const float* __restrict__ Vw,
                                                  const float* __restrict__ bV,
                                                  float* __restrict__ scores,
                                                  float* __restrict__ pm,
                                                  float* __restrict__ ps,
                                                  float* __restrict__ pctx) {
    __shared__ __align__(16) ushort Al[64][264];   // 33.8 KB
    __shared__ float sred[4][64];                  // 1 KB   [u-quad][t-row]
    __shared__ f32x4 cred[4][64];                  // 4 KB   (two-phase)
    const int tid = threadIdx.x;
    const int b = blockIdx.y, c = blockIdx.x;
    const int t0 = c * 64;
    const int wid = tid >> 6, lane = tid & 63;
    const int l15 = lane & 15, hi = lane >> 4;
    const int wr = wid >> 2, wc = wid & 3;

    // stage A: 64 rows x 256 d, fp32 coalesced -> HW bf16 -> LDS (8 waves split)
    const float* vbase = values + ((size_t)b * Tn + t0) * Dn;
    #pragma unroll
    for (int i = 0; i < 4; ++i) {
        int flat = i * 4096 + tid * 8;
        int row = flat >> 8, col = flat & 255;
        const float4 f0 = *(const float4*)&vbase[row * Dn + col];
        const float4 f1 = *(const float4*)&vbase[row * Dn + col + 4];
        s16x8 p;
        p[0] = (short)f2bf_hw(f0.x); p[1] = (short)f2bf_hw(f0.y);
        p[2] = (short)f2bf_hw(f0.z); p[3] = (short)f2bf_hw(f0.w);
        p[4] = (short)f2bf_hw(f1.x); p[5] = (short)f2bf_hw(f1.y);
        p[6] = (short)f2bf_hw(f1.z); p[7] = (short)f2bf_hw(f1.w);
        *(s16x8*)&Al[row][col] = p;
    }

    const ushort* wbase = W1T + (size_t)(wc * 64 + l15) * Dn + hi * 8;

    f32x4 acc[2][4];
    #pragma unroll
    for (int tt = 0; tt < 2; ++tt)
        #pragma unroll
        for (int ut = 0; ut < 4; ++ut) acc[tt][ut] = (f32x4){0.f, 0.f, 0.f, 0.f};

    // B prefetch depth 1
    s16x8 bcur[4], bnxt[4];
    #pragma unroll
    for (int ut = 0; ut < 4; ++ut)
        bcur[ut] = *(const s16x8*)&wbase[(size_t)ut * 16 * Dn];

    __syncthreads();  // B1: A tile ready

    #pragma unroll
    for (int kc = 0; kc < 8; ++kc) {
        if (kc < 7) {
            #pragma unroll
            for (int ut = 0; ut < 4; ++ut)
                bnxt[ut] = *(const s16x8*)&wbase[(size_t)ut * 16 * Dn + (kc + 1) * 32];
        }
        const int k0 = kc * 32;
        s16x8 af[2];
        #pragma unroll
        for (int tt = 0; tt < 2; ++tt)
            af[tt] = *(const s16x8*)&Al[wr * 32 + tt * 16 + l15][k0 + hi * 8];
        #pragma unroll
        for (int tt = 0; tt < 2; ++tt)
            #pragma unroll
            for (int ut = 0; ut < 4; ++ut)
                acc[tt][ut] = __builtin_amdgcn_mfma_f32_16x16x32_bf16(af[tt], bcur[ut], acc[tt][ut], 0, 0, 0);
        if (kc < 7) {
            #pragma unroll
            for (int ut = 0; ut < 4; ++ut) bcur[ut] = bnxt[ut];
        }
    }

    // epilogue constants
    float Vreg[4], qreg[4];
    #pragma unroll
    for (int ut = 0; ut < 4; ++ut) {
        int u = wc * 64 + ut * 16 + l15;
        Vreg[ut] = Vw[u];
        qreg[ut] = qb[b * Un + u];
    }

    // acc[tt][ut][i] = proj[t = t0+wr*32+tt*16+hi*4+i][u = wc*64+ut*16+l15]
    float psc[2][4];
    #pragma unroll
    for (int tt = 0; tt < 2; ++tt)
        #pragma unroll
        for (int i = 0; i < 4; ++i) psc[tt][i] = 0.f;
    #pragma unroll
    for (int tt = 0; tt < 2; ++tt)
        #pragma unroll
        for (int ut = 0; ut < 4; ++ut)
            #pragma unroll
            for (int i = 0; i < 4; ++i)
                psc[tt][i] += tanh5(acc[tt][ut][i] + qreg[ut]) * Vreg[ut];

    #pragma unroll
    for (int tt = 0; tt < 2; ++tt)
        #pragma unroll
        for (int i = 0; i < 4; ++i) {
            float v = psc[tt][i];
            v += __shfl_xor(v, 1, 64);
            v += __shfl_xor(v, 2, 64);
            v += __shfl_xor(v, 4, 64);
            v += __shfl_xor(v, 8, 64);
            if (l15 == 0) sred[wc][wr * 32 + tt * 16 + hi * 4 + i] = v;
        }
    __syncthreads();  // B2: sred ready

    // redundant wave-parallel flash over 64 rows (row = lane)
    float s = sred[0][lane] + sred[1][lane] + sred[2][lane] + sred[3][lane] + bV[0];
    if (wid == 0) scores[b * Tn + t0 + lane] = s;
    float m = s;
    #pragma unroll
    for (int off = 32; off > 0; off >>= 1) m = fmaxf(m, __shfl_xor(m, off, 64));
    const float p = __expf(s - m);
    float S = p;
    #pragma unroll
    for (int off = 32; off > 0; off >>= 1) S += __shfl_xor(S, off, 64);

    // context partial from bf16 tile; 8 waves split t (8 rows each)
    const int d4 = lane * 4;
    f32x4 loc = (f32x4){0.f, 0.f, 0.f, 0.f};
    #pragma unroll
    for (int k = 0; k < 8; ++k) {
        const int t = wid + 8 * k;
        const float pk = __shfl(p, t, 64);    // uniform source -> broadcast
        const s16x4 v = *(const s16x4*)&Al[t][d4];
        loc[0] += pk * bf2f((ushort)v[0]);
        loc[1] += pk * bf2f((ushort)v[1]);
        loc[2] += pk * bf2f((ushort)v[2]);
        loc[3] += pk * bf2f((ushort)v[3]);
    }
    // two-phase cross-wave reduce (keeps cred at 4 KB)
    if (wid < 4) cred[wid][lane] = loc;
    __syncthreads();  // B3a
    if (wid >= 4) {
        f32x4 t = cred[wid - 4][lane];
        cred[wid - 4][lane] = t + loc;
    }
    __syncthreads();  // B3b
    if (wid == 0) {
        const f32x4 o = cred[0][lane] + cred[1][lane] + cred[2][lane] + cred[3][lane];
        *(f32x4*)&pctx[((size_t)(b * CH + c)) * Dn + d4] = o;
    }
    if (tid == 0) { pm[b * CH + c] = m; ps[b * CH + c] = S; }
}

// K2: per-batch flash reduce over CH chunk partials.
__global__ __launch_bounds__(256) void k_reduce(const float* __restrict__ pm,
                                                const float* __restrict__ ps,
                                                const float* __restrict__ pctx,
                                                float* __restrict__ context,
                                                float* __restrict__ MS) {
    const int b = blockIdx.x, d = threadIdx.x;
    float M = -1e30f;
    #pragma unroll 8
    for (int c = 0; c < CH; ++c) M = fmaxf(M, pm[b * CH + c]);
    float S = 0.f, ctx = 0.f;
    #pragma unroll 4
    for (int c = 0; c < CH; ++c) {
        const float w = __expf(pm[b * CH + c] - M);
        S += w * ps[b * CH + c];
        ctx += w * pctx[((size_t)(b * CH + c)) * Dn + d];
    }
    context[b * Dn + d] = __fdividef(ctx, S);
    if (d == 0) { MS[b * 2] = M; MS[b * 2 + 1] = S; }
}

// K3: attn[b,t] = exp(score - M_b) / S_b, in place.
__global__ __launch_bounds__(256) void k_attn(float* __restrict__ attn,
                                              const float* __restrict__ MS) {
    const int b = blockIdx.y;
    const int base = b * Tn + blockIdx.x * 1024 + threadIdx.x * 4;
    const float M = MS[b * 2];
    const float invS = __fdividef(1.0f, MS[b * 2 + 1]);
    float4 s = *(const float4*)&attn[base];
    s.x = __expf(s.x - M) * invS;
    s.y = __expf(s.y - M) * invS;
    s.z = __expf(s.z - M) * invS;
    s.w = __expf(s.w - M) * invS;
    *(float4*)&attn[base] = s;
}

extern "C" void kernel_launch(void* const* d_in, const int* in_sizes, int n_in,
                              void* d_out, int out_size, void* d_ws, size_t ws_size,
                              hipStream_t stream) {
    const float* query  = (const float*)d_in[0];
    const float* values = (const float*)d_in[1];
    const float* W1     = (const float*)d_in[2];
    const float* b1     = (const float*)d_in[3];
    const float* W2     = (const float*)d_in[4];
    const float* b2     = (const float*)d_in[5];
    const float* Vw     = (const float*)d_in[6];
    const float* bV     = (const float*)d_in[7];

    float* context = (float*)d_out;            // [B,D]
    float* attn    = (float*)d_out + Bn * Dn;  // [B,T,1] — raw scores, then attn in place

    float*  pctx = (float*)d_ws;                       // [B, CH, D] = 2 MB
    float*  pm   = pctx + (size_t)Bn * CH * Dn;        // [B, CH]
    float*  ps   = pm + Bn * CH;                       // [B, CH]
    float*  qb   = ps + Bn * CH;                       // [B, U]
    float*  MS   = qb + Bn * Un;                       // [B, 2]
    ushort* W1T  = (ushort*)(MS + Bn * 2);             // [U, D] bf16

    k_prep<<<dim3(256 + Bn), dim3(256), 0, stream>>>(W1, W1T, query, W2, b1, b2, qb);
    k_fused<<<dim3(CH, Bn), dim3(512), 0, stream>>>(values, W1T, qb, Vw, bV,
                                                    attn, pm, ps, pctx);
    k_reduce<<<dim3(Bn), dim3(256), 0, stream>>>(pm, ps, pctx, context, MS);
    k_attn<<<dim3(Tn / 1024, Bn), dim3(256), 0, stream>>>(attn, MS);
}